// Round 3
// baseline (729.843 us; speedup 1.0000x reference)
//
#include <hip/hip_runtime.h>
#include <cstdint>
#include <cstddef>

#define H 256
#define LDA2 72       // padded LDS row stride (bf16 elems): uniform bank spread

typedef __attribute__((ext_vector_type(8))) short  frag8;     // 8 bf16 (4 VGPRs)
typedef __attribute__((ext_vector_type(8))) unsigned short ushort8;
typedef __attribute__((ext_vector_type(4))) float  f32x4;

__device__ __forceinline__ unsigned short f32_to_bf16(float f) {
    uint32_t u = __float_as_uint(f);
    u = (u + 0x7FFFu + ((u >> 16) & 1u)) >> 16;   // RNE
    return (unsigned short)u;
}

// ---------------- kernel 1: prep — Wopt fragment-shuffle + Wout transpose ----------------
// Wopt layout: [ct(16)][ksg(16)][lane(64)][8 bf16] so a wave's B-frag load is one
// coalesced dwordx4: value = Wcat[col = ct*16+(lane&15)][k = ksg*32+(lane>>4)*8+j],
// Wcat = concat(Wu, Wv) along k.
__global__ void prep(const float* __restrict__ Wu, const float* __restrict__ Wv,
                     const float* __restrict__ Wout,
                     unsigned short* __restrict__ Wopt, float* __restrict__ WoutT) {
    int bid = blockIdx.x, tid = threadIdx.x;
    if (bid < 64) {
        int idx  = bid * 256 + tid;        // 0..16383
        int lane = idx & 63;
        int ksg  = (idx >> 6) & 15;
        int ct   = idx >> 10;
        int col  = ct * 16 + (lane & 15);
        int kg   = ksg * 32 + (lane >> 4) * 8;
        ushort8 pk;
        #pragma unroll
        for (int j = 0; j < 8; j++) {
            int k = kg + j;
            float v = (k < 256) ? Wu[col * 256 + k] : Wv[col * 256 + (k - 256)];
            pk[j] = f32_to_bf16(v);
        }
        *(ushort8*)&Wopt[(size_t)idx * 8] = pk;
    } else {
        int t2 = (bid - 64) * 256 + tid;   // 0..65535
        int j = t2 & 255, k = t2 >> 8;
        WoutT[t2] = Wout[j * 256 + k];     // WoutT[k][j] = Wout[j][k]
    }
}

// ---------------- kernel 2: exclusive scan of ragged lengths ----------------
__global__ void seg_offsets(const int* __restrict__ lens, int B, int* __restrict__ off) {
    __shared__ int part[256];
    int tid = threadIdx.x;
    bool is64 = (B >= 3) && (lens[1] == 0) && (lens[3] == 0) && (lens[5] == 0);
    int per = (B + 255) / 256;
    int base = tid * per;
    int s = 0;
    for (int i = 0; i < per; i++) {
        int idx = base + i;
        if (idx < B) s += is64 ? lens[2 * idx] : lens[idx];
    }
    part[tid] = s;
    __syncthreads();
    for (int d = 1; d < 256; d <<= 1) {
        int v = part[tid];
        int add = (tid >= d) ? part[tid - d] : 0;
        __syncthreads();
        part[tid] = v + add;
        __syncthreads();
    }
    int run = part[tid] - s;
    for (int i = 0; i < per; i++) {
        int idx = base + i;
        if (idx < B) {
            off[idx] = run;
            run += is64 ? lens[2 * idx] : lens[idx];
        }
    }
    if (tid == 255) off[B] = part[255];
}

// ---------------- kernel 3: fused e = We . sigmoid(Wu f + bu + Wv c) ----------------
// 256 thr (4 waves). Block = 64 rows x 256 cols, K=512 in 8 steps of KT=64.
// Wave w owns cols [64w, 64w+64). Register-prefetch of next A strip overlaps MFMA.
__global__ __launch_bounds__(256) void fused_e(
        const float* __restrict__ feats, const float* __restrict__ ctx,
        const unsigned short* __restrict__ Wopt,
        const float* __restrict__ bu, const float* __restrict__ We,
        float* __restrict__ e_out) {
    __shared__ unsigned short a_lds[64 * LDA2];   // 9216 B, bf16 A-tile 64x64(+pad)
    __shared__ float e_part[4 * 64];

    const int tid  = threadIdx.x;
    const int lane = tid & 63;
    const int w    = tid >> 6;
    const int l15  = lane & 15;
    const int q    = lane >> 4;
    const size_t m0 = (size_t)blockIdx.x * 64;
    const int srow = tid >> 2;     // staging row 0..63
    const int q4   = tid & 3;      // staging 16-float chunk

    f32x4 acc[4][4];
    #pragma unroll
    for (int i = 0; i < 4; i++)
        #pragma unroll
        for (int j = 0; j < 4; j++)
            acc[i][j] = (f32x4)(0.0f);

    // prefetch KT 0
    f32x4 pre[4];
    {
        const float* p = feats + (m0 + srow) * H + q4 * 16;
        pre[0] = *(const f32x4*)p;       pre[1] = *(const f32x4*)(p + 4);
        pre[2] = *(const f32x4*)(p + 8); pre[3] = *(const f32x4*)(p + 12);
    }

    for (int kt = 0; kt < 8; ++kt) {
        // pack 16 floats -> 2x ushort8
        ushort8 lo, hi;
        #pragma unroll
        for (int j = 0; j < 4; j++) {
            lo[j]     = f32_to_bf16(pre[0][j]);
            lo[j + 4] = f32_to_bf16(pre[1][j]);
            hi[j]     = f32_to_bf16(pre[2][j]);
            hi[j + 4] = f32_to_bf16(pre[3][j]);
        }
        __syncthreads();                  // prior KT's frag reads done
        *(ushort8*)&a_lds[srow * LDA2 + q4 * 16]     = lo;
        *(ushort8*)&a_lds[srow * LDA2 + q4 * 16 + 8] = hi;
        __syncthreads();                  // writes visible

        if (kt < 7) {                     // prefetch next strip; overlaps MFMA below
            int ktn = kt + 1;
            const float* src = (ktn < 4) ? feats : ctx;
            const float* p = src + (m0 + srow) * H + (ktn & 3) * 64 + q4 * 16;
            pre[0] = *(const f32x4*)p;       pre[1] = *(const f32x4*)(p + 4);
            pre[2] = *(const f32x4*)(p + 8); pre[3] = *(const f32x4*)(p + 12);
        }

        #pragma unroll
        for (int ks = 0; ks < 2; ++ks) {
            const int ksg = kt * 2 + ks;
            frag8 afr[4], bfr[4];
            #pragma unroll
            for (int ci = 0; ci < 4; ++ci)
                bfr[ci] = *(const frag8*)&Wopt[((((size_t)(w * 4 + ci) * 16) + ksg) * 64 + lane) * 8];
            #pragma unroll
            for (int rt = 0; rt < 4; ++rt)
                afr[rt] = *(const frag8*)&a_lds[(rt * 16 + l15) * LDA2 + ks * 32 + q * 8];
            #pragma unroll
            for (int rt = 0; rt < 4; ++rt)
                #pragma unroll
                for (int ci = 0; ci < 4; ++ci)
                    acc[rt][ci] = __builtin_amdgcn_mfma_f32_16x16x32_bf16(
                        afr[rt], bfr[ci], acc[rt][ci], 0, 0, 0);
        }
    }

    // epilogue: e_row = sum_col We[col] * sigmoid(h + bu[col]); deterministic partials
    float buv[4], wev[4];
    #pragma unroll
    for (int ci = 0; ci < 4; ++ci) {
        int col = w * 64 + ci * 16 + l15;
        buv[ci] = bu[col];
        wev[ci] = We[col];
    }
    #pragma unroll
    for (int rt = 0; rt < 4; ++rt) {
        #pragma unroll
        for (int r = 0; r < 4; ++r) {
            float s = 0.0f;
            #pragma unroll
            for (int ci = 0; ci < 4; ++ci) {
                float h = acc[rt][ci][r] + buv[ci];
                s += wev[ci] / (1.0f + __expf(-h));
            }
            s += __shfl_xor(s, 1, 64);
            s += __shfl_xor(s, 2, 64);
            s += __shfl_xor(s, 4, 64);
            s += __shfl_xor(s, 8, 64);
            if (l15 == 0) e_part[w * 64 + rt * 16 + q * 4 + r] = s;
        }
    }
    __syncthreads();
    if (tid < 64)
        e_out[m0 + tid] = e_part[tid] + e_part[64 + tid] + e_part[128 + tid] + e_part[192 + tid];
}

// ---------------- kernel 4: per-segment softmax + weighted pooling ----------------
// Robust to arbitrary len (last segment ~2100). 4 barriers total; float4 pooling.
__global__ __launch_bounds__(256) void softmax_pool(
        const float* __restrict__ e, const float* __restrict__ feats,
        const int* __restrict__ off, float* __restrict__ rst) {
    __shared__ float redw[8];
    __shared__ float redf[4 * 256];
    const int b = blockIdx.x, tid = threadIdx.x;
    const int lane = tid & 63, g = tid >> 6;
    const int start = off[b];
    const int len = off[b + 1] - start;

    // --- max: grid-stride + wave shfl + 4-entry combine ---
    float mloc = -3.0e38f;
    for (int i = tid; i < len; i += 256) mloc = fmaxf(mloc, e[start + i]);
    #pragma unroll
    for (int o = 32; o > 0; o >>= 1) mloc = fmaxf(mloc, __shfl_xor(mloc, o, 64));
    if (lane == 0) redw[g] = mloc;
    __syncthreads();
    float m = fmaxf(fmaxf(redw[0], redw[1]), fmaxf(redw[2], redw[3]));

    // --- sum of exp ---
    float sloc = 0.0f;
    for (int i = tid; i < len; i += 256) sloc += expf(e[start + i] - m);
    #pragma unroll
    for (int o = 32; o > 0; o >>= 1) sloc += __shfl_xor(sloc, o, 64);
    if (lane == 0) redw[4 + g] = sloc;
    __syncthreads();
    float denom = redw[4] + redw[5] + redw[6] + redw[7];
    float inv = (denom > 0.0f) ? 1.0f / denom : 0.0f;

    // --- pooling: wave g takes rows i == g (mod 4), float4 cols ---
    f32x4 acc4 = (f32x4)(0.0f);
    const f32x4* feats4 = (const f32x4*)feats;
    for (int i = g; i < len; i += 4) {
        float a = expf(e[start + i] - m) * inv;
        f32x4 v = feats4[(size_t)(start + i) * 64 + lane];
        acc4 += a * v;
    }
    *(f32x4*)&redf[g * 256 + lane * 4] = acc4;
    __syncthreads();
    rst[(size_t)b * H + tid] =
        redf[tid] + redf[256 + tid] + redf[512 + tid] + redf[768 + tid];
}

// ---------------- kernel 5: out = rst @ Wout.T (via WoutT) ----------------
#define RB 8
__global__ __launch_bounds__(256) void out_gemm(
        const float* __restrict__ rst, const float* __restrict__ WoutT,
        float* __restrict__ out) {
    __shared__ float r[RB * 256];
    const int tid = threadIdx.x;
    const size_t b0 = (size_t)blockIdx.x * RB;
    for (int i = tid; i < RB * 256; i += 256) r[i] = rst[b0 * 256 + i];
    __syncthreads();
    float acc[RB];
    #pragma unroll
    for (int j = 0; j < RB; j++) acc[j] = 0.0f;
    for (int k = 0; k < 256; k += 4) {
        f32x4 rw[RB];
        #pragma unroll
        for (int j = 0; j < RB; j++) rw[j] = *(const f32x4*)&r[j * 256 + k];
        #pragma unroll
        for (int kk = 0; kk < 4; kk++) {
            float wv = WoutT[(size_t)(k + kk) * 256 + tid];
            #pragma unroll
            for (int j = 0; j < RB; j++) acc[j] += rw[j][kk] * wv;
        }
    }
    #pragma unroll
    for (int j = 0; j < RB; j++) out[(b0 + j) * 256 + tid] = acc[j];
}

// ---------------- launch ----------------
extern "C" void kernel_launch(void* const* d_in, const int* in_sizes, int n_in,
                              void* d_out, int out_size, void* d_ws, size_t ws_size,
                              hipStream_t stream) {
    const float* feats = (const float*)d_in[0];
    const float* ctx   = (const float*)d_in[1];
    const int*   lens  = (const int*)d_in[2];
    const float* Wu    = (const float*)d_in[3];
    const float* bu    = (const float*)d_in[4];
    const float* Wv    = (const float*)d_in[5];
    const float* We    = (const float*)d_in[6];
    const float* Wout  = (const float*)d_in[7];
    float* out = (float*)d_out;

    const int N = in_sizes[0] / H;    // 204800
    const int B = in_sizes[2];        // 4096

    char* w = (char*)d_ws;
    auto carve = [&](size_t bytes) {
        char* p = w;
        w += (bytes + 255) & ~(size_t)255;
        return p;
    };
    int*            off   = (int*)           carve((size_t)(B + 1) * sizeof(int));
    float*          e     = (float*)         carve((size_t)N * sizeof(float));
    float*          rst   = (float*)         carve((size_t)B * H * sizeof(float));
    unsigned short* Wopt  = (unsigned short*)carve((size_t)16 * 16 * 64 * 8 * sizeof(unsigned short));
    float*          WoutT = (float*)         carve((size_t)H * H * sizeof(float));

    prep        <<<320,     256, 0, stream>>>(Wu, Wv, Wout, Wopt, WoutT);
    seg_offsets <<<1,       256, 0, stream>>>(lens, B, off);
    fused_e     <<<N / 64,  256, 0, stream>>>(feats, ctx, Wopt, bu, We, e);
    softmax_pool<<<B,       256, 0, stream>>>(e, feats, off, rst);
    out_gemm    <<<B / RB,  256, 0, stream>>>(rst, WoutT, out);
}

// Round 4
// 561.682 us; speedup vs baseline: 1.2994x; 1.2994x over previous
//
#include <hip/hip_runtime.h>
#include <cstdint>
#include <cstddef>

#define H 256
#define LDA2 72       // padded LDS row stride (bf16 elems): uniform bank spread
#define CHUNK 128     // max items per pooling chunk

typedef __attribute__((ext_vector_type(8))) short  frag8;     // 8 bf16 (4 VGPRs)
typedef __attribute__((ext_vector_type(8))) unsigned short ushort8;
typedef __attribute__((ext_vector_type(4))) float  f32x4;

__device__ __forceinline__ unsigned short f32_to_bf16(float f) {
    uint32_t u = __float_as_uint(f);
    u = (u + 0x7FFFu + ((u >> 16) & 1u)) >> 16;   // RNE
    return (unsigned short)u;
}

// ---------------- kernel 1: prep — Wopt fragment-shuffle + Wout transpose ----------------
// Wopt layout: [ct(16)][ksg(16)][lane(64)][8 bf16]: wave B-frag load = one coalesced
// dwordx4. value = Wcat[col = ct*16+(lane&15)][k = ksg*32+(lane>>4)*8+j], Wcat=concat(Wu,Wv).
__global__ void prep(const float* __restrict__ Wu, const float* __restrict__ Wv,
                     const float* __restrict__ Wout,
                     unsigned short* __restrict__ Wopt, float* __restrict__ WoutT) {
    int bid = blockIdx.x, tid = threadIdx.x;
    if (bid < 64) {
        int idx  = bid * 256 + tid;        // 0..16383
        int lane = idx & 63;
        int ksg  = (idx >> 6) & 15;
        int ct   = idx >> 10;
        int col  = ct * 16 + (lane & 15);
        int kg   = ksg * 32 + (lane >> 4) * 8;
        ushort8 pk;
        #pragma unroll
        for (int j = 0; j < 8; j++) {
            int k = kg + j;
            float v = (k < 256) ? Wu[col * 256 + k] : Wv[col * 256 + (k - 256)];
            pk[j] = f32_to_bf16(v);
        }
        *(ushort8*)&Wopt[(size_t)idx * 8] = pk;
    } else {
        int t2 = (bid - 64) * 256 + tid;   // 0..65535
        int j = t2 & 255, k = t2 >> 8;
        WoutT[t2] = Wout[j * 256 + k];     // WoutT[k][j] = Wout[j][k]
    }
}

// ---------------- kernel 2: dual exclusive scan: item offsets + chunk work-list ----------------
// Chunks of <=CHUNK items per segment, emitted deterministically (no atomics).
__global__ void seg_offsets(const int* __restrict__ lens, int B, int* __restrict__ off,
                            int2* __restrict__ chunks, int* __restrict__ chunk_cnt) {
    __shared__ int partL[256], partC[256];
    int tid = threadIdx.x;
    bool is64 = (B >= 3) && (lens[1] == 0) && (lens[3] == 0) && (lens[5] == 0);
    int per = (B + 255) / 256;
    int base = tid * per;
    int sL = 0, sC = 0;
    for (int i = 0; i < per; i++) {
        int idx = base + i;
        if (idx < B) {
            int l = is64 ? lens[2 * idx] : lens[idx];
            sL += l;
            sC += (l + CHUNK - 1) / CHUNK;
        }
    }
    partL[tid] = sL; partC[tid] = sC;
    __syncthreads();
    for (int d = 1; d < 256; d <<= 1) {
        int vL = partL[tid], vC = partC[tid];
        int aL = (tid >= d) ? partL[tid - d] : 0;
        int aC = (tid >= d) ? partC[tid - d] : 0;
        __syncthreads();
        partL[tid] = vL + aL; partC[tid] = vC + aC;
        __syncthreads();
    }
    int runL = partL[tid] - sL;   // exclusive prefixes
    int runC = partC[tid] - sC;
    for (int i = 0; i < per; i++) {
        int idx = base + i;
        if (idx < B) {
            int l = is64 ? lens[2 * idx] : lens[idx];
            off[idx] = runL;
            int n = (l + CHUNK - 1) / CHUNK;
            for (int c = 0; c < n; c++)
                chunks[runC + c] = make_int2(idx, runL + c * CHUNK);
            runC += n;
            runL += l;
        }
    }
    if (tid == 255) { off[B] = partL[255]; chunk_cnt[0] = partC[255]; }
}

// ---------------- kernel 3: fused e = We . sigmoid(Wu f + bu + Wv c) ----------------
__global__ __launch_bounds__(256) void fused_e(
        const float* __restrict__ feats, const float* __restrict__ ctx,
        const unsigned short* __restrict__ Wopt,
        const float* __restrict__ bu, const float* __restrict__ We,
        float* __restrict__ e_out) {
    __shared__ unsigned short a_lds[64 * LDA2];   // 9216 B
    __shared__ float e_part[4 * 64];

    const int tid  = threadIdx.x;
    const int lane = tid & 63;
    const int w    = tid >> 6;
    const int l15  = lane & 15;
    const int q    = lane >> 4;
    const size_t m0 = (size_t)blockIdx.x * 64;
    const int srow = tid >> 2;
    const int q4   = tid & 3;

    f32x4 acc[4][4];
    #pragma unroll
    for (int i = 0; i < 4; i++)
        #pragma unroll
        for (int j = 0; j < 4; j++)
            acc[i][j] = (f32x4)(0.0f);

    f32x4 pre[4];
    {
        const float* p = feats + (m0 + srow) * H + q4 * 16;
        pre[0] = *(const f32x4*)p;       pre[1] = *(const f32x4*)(p + 4);
        pre[2] = *(const f32x4*)(p + 8); pre[3] = *(const f32x4*)(p + 12);
    }

    for (int kt = 0; kt < 8; ++kt) {
        ushort8 lo, hi;
        #pragma unroll
        for (int j = 0; j < 4; j++) {
            lo[j]     = f32_to_bf16(pre[0][j]);
            lo[j + 4] = f32_to_bf16(pre[1][j]);
            hi[j]     = f32_to_bf16(pre[2][j]);
            hi[j + 4] = f32_to_bf16(pre[3][j]);
        }
        __syncthreads();
        *(ushort8*)&a_lds[srow * LDA2 + q4 * 16]     = lo;
        *(ushort8*)&a_lds[srow * LDA2 + q4 * 16 + 8] = hi;
        __syncthreads();

        if (kt < 7) {
            int ktn = kt + 1;
            const float* src = (ktn < 4) ? feats : ctx;
            const float* p = src + (m0 + srow) * H + (ktn & 3) * 64 + q4 * 16;
            pre[0] = *(const f32x4*)p;       pre[1] = *(const f32x4*)(p + 4);
            pre[2] = *(const f32x4*)(p + 8); pre[3] = *(const f32x4*)(p + 12);
        }

        #pragma unroll
        for (int ks = 0; ks < 2; ++ks) {
            const int ksg = kt * 2 + ks;
            frag8 afr[4], bfr[4];
            #pragma unroll
            for (int ci = 0; ci < 4; ++ci)
                bfr[ci] = *(const frag8*)&Wopt[((((size_t)(w * 4 + ci) * 16) + ksg) * 64 + lane) * 8];
            #pragma unroll
            for (int rt = 0; rt < 4; ++rt)
                afr[rt] = *(const frag8*)&a_lds[(rt * 16 + l15) * LDA2 + ks * 32 + q * 8];
            #pragma unroll
            for (int rt = 0; rt < 4; ++rt)
                #pragma unroll
                for (int ci = 0; ci < 4; ++ci)
                    acc[rt][ci] = __builtin_amdgcn_mfma_f32_16x16x32_bf16(
                        afr[rt], bfr[ci], acc[rt][ci], 0, 0, 0);
        }
    }

    float buv[4], wev[4];
    #pragma unroll
    for (int ci = 0; ci < 4; ++ci) {
        int col = w * 64 + ci * 16 + l15;
        buv[ci] = bu[col];
        wev[ci] = We[col];
    }
    #pragma unroll
    for (int rt = 0; rt < 4; ++rt) {
        #pragma unroll
        for (int r = 0; r < 4; ++r) {
            float s = 0.0f;
            #pragma unroll
            for (int ci = 0; ci < 4; ++ci) {
                float h = acc[rt][ci][r] + buv[ci];
                s += wev[ci] / (1.0f + __expf(-h));
            }
            s += __shfl_xor(s, 1, 64);
            s += __shfl_xor(s, 2, 64);
            s += __shfl_xor(s, 4, 64);
            s += __shfl_xor(s, 8, 64);
            if (l15 == 0) e_part[w * 64 + rt * 16 + q * 4 + r] = s;
        }
    }
    __syncthreads();
    if (tid < 64)
        e_out[m0 + tid] = e_part[tid] + e_part[64 + tid] + e_part[128 + tid] + e_part[192 + tid];
}

// ---------------- kernel 4: per-segment softmax stats (one wave per segment) ----------------
__global__ __launch_bounds__(256) void seg_stats(
        const float* __restrict__ e, const int* __restrict__ off, int B,
        float* __restrict__ m_arr, float* __restrict__ inv_arr) {
    int seg = blockIdx.x * 4 + (threadIdx.x >> 6);
    int lane = threadIdx.x & 63;
    if (seg >= B) return;
    int start = off[seg];
    int len = off[seg + 1] - start;
    float m = -3.0e38f;
    for (int i = lane; i < len; i += 64) m = fmaxf(m, e[start + i]);
    #pragma unroll
    for (int o = 32; o > 0; o >>= 1) m = fmaxf(m, __shfl_xor(m, o, 64));
    float s = 0.0f;
    for (int i = lane; i < len; i += 64) s += expf(e[start + i] - m);
    #pragma unroll
    for (int o = 32; o > 0; o >>= 1) s += __shfl_xor(s, o, 64);
    if (lane == 0) {
        m_arr[seg] = m;
        inv_arr[seg] = (s > 0.0f) ? 1.0f / s : 0.0f;
    }
}

// ---------------- kernel 5: chunked weighted pooling ----------------
// One block per <=CHUNK-item chunk; long segments get multiple blocks (atomic combine).
__global__ __launch_bounds__(256) void pool_chunks(
        const float* __restrict__ e, const float* __restrict__ feats,
        const int* __restrict__ off, const int2* __restrict__ chunks,
        const int* __restrict__ chunk_cnt,
        const float* __restrict__ m_arr, const float* __restrict__ inv_arr,
        float* __restrict__ rst) {
    __shared__ float redf[4 * 256];
    int idx = blockIdx.x;
    if (idx >= chunk_cnt[0]) return;
    int2 en = chunks[idx];
    int seg = en.x, cstart = en.y;
    int sstart = off[seg], send = off[seg + 1];
    int clen = send - cstart;
    if (clen > CHUNK) clen = CHUNK;
    float m = m_arr[seg], inv = inv_arr[seg];
    int tid = threadIdx.x, lane = tid & 63, g = tid >> 6;

    f32x4 acc = (f32x4)(0.0f);
    const f32x4* feats4 = (const f32x4*)feats;
    for (int i = g; i < clen; i += 4) {
        float a = expf(e[cstart + i] - m) * inv;
        acc += a * feats4[(size_t)(cstart + i) * 64 + lane];
    }
    *(f32x4*)&redf[g * 256 + lane * 4] = acc;
    __syncthreads();
    float v = redf[tid] + redf[256 + tid] + redf[512 + tid] + redf[768 + tid];
    if (send - sstart > CHUNK) atomicAdd(&rst[(size_t)seg * H + tid], v);
    else rst[(size_t)seg * H + tid] = v;
}

// ---------------- kernel 6: out = rst @ Wout.T (via WoutT) ----------------
#define RB 8
__global__ __launch_bounds__(256) void out_gemm(
        const float* __restrict__ rst, const float* __restrict__ WoutT,
        float* __restrict__ out) {
    __shared__ float r[RB * 256];
    const int tid = threadIdx.x;
    const size_t b0 = (size_t)blockIdx.x * RB;
    for (int i = tid; i < RB * 256; i += 256) r[i] = rst[b0 * 256 + i];
    __syncthreads();
    float acc[RB];
    #pragma unroll
    for (int j = 0; j < RB; j++) acc[j] = 0.0f;
    for (int k = 0; k < 256; k += 4) {
        f32x4 rw[RB];
        #pragma unroll
        for (int j = 0; j < RB; j++) rw[j] = *(const f32x4*)&r[j * 256 + k];
        #pragma unroll
        for (int kk = 0; kk < 4; kk++) {
            float wv = WoutT[(size_t)(k + kk) * 256 + tid];
            #pragma unroll
            for (int j = 0; j < RB; j++) acc[j] += rw[j][kk] * wv;
        }
    }
    #pragma unroll
    for (int j = 0; j < RB; j++) out[(b0 + j) * 256 + tid] = acc[j];
}

// ---------------- launch ----------------
extern "C" void kernel_launch(void* const* d_in, const int* in_sizes, int n_in,
                              void* d_out, int out_size, void* d_ws, size_t ws_size,
                              hipStream_t stream) {
    const float* feats = (const float*)d_in[0];
    const float* ctx   = (const float*)d_in[1];
    const int*   lens  = (const int*)d_in[2];
    const float* Wu    = (const float*)d_in[3];
    const float* bu    = (const float*)d_in[4];
    const float* Wv    = (const float*)d_in[5];
    const float* We    = (const float*)d_in[6];
    const float* Wout  = (const float*)d_in[7];
    float* out = (float*)d_out;

    const int N = in_sizes[0] / H;    // 204800
    const int B = in_sizes[2];        // 4096
    const int maxChunks = B + (N + CHUNK - 1) / CHUNK;   // worst-case work-list size

    char* w = (char*)d_ws;
    auto carve = [&](size_t bytes) {
        char* p = w;
        w += (bytes + 255) & ~(size_t)255;
        return p;
    };
    int*            off    = (int*)           carve((size_t)(B + 1) * sizeof(int));
    float*          e      = (float*)         carve((size_t)N * sizeof(float));
    float*          rst    = (float*)         carve((size_t)B * H * sizeof(float));
    unsigned short* Wopt   = (unsigned short*)carve((size_t)16 * 16 * 64 * 8 * sizeof(unsigned short));
    float*          WoutT  = (float*)         carve((size_t)H * H * sizeof(float));
    int2*           chunks = (int2*)          carve((size_t)maxChunks * sizeof(int2));
    int*            ccnt   = (int*)           carve(sizeof(int));
    float*          m_arr  = (float*)         carve((size_t)B * sizeof(float));
    float*          i_arr  = (float*)         carve((size_t)B * sizeof(float));

    hipMemsetAsync(rst, 0, (size_t)B * H * sizeof(float), stream);  // for atomic combine

    prep        <<<320,           256, 0, stream>>>(Wu, Wv, Wout, Wopt, WoutT);
    seg_offsets <<<1,             256, 0, stream>>>(lens, B, off, chunks, ccnt);
    fused_e     <<<N / 64,        256, 0, stream>>>(feats, ctx, Wopt, bu, We, e);
    seg_stats   <<<(B + 3) / 4,   256, 0, stream>>>(e, off, B, m_arr, i_arr);
    pool_chunks <<<maxChunks,     256, 0, stream>>>(e, feats, off, chunks, ccnt, m_arr, i_arr, rst);
    out_gemm    <<<B / RB,        256, 0, stream>>>(rst, WoutT, out);
}

// Round 5
// 537.296 us; speedup vs baseline: 1.3584x; 1.0454x over previous
//
#include <hip/hip_runtime.h>
#include <hip/hip_bf16.h>
#include <cstdint>
#include <cstddef>

#define H 256
#define CHUNK 128     // max items per pooling chunk

typedef __attribute__((ext_vector_type(8))) short    frag8;   // 8 bf16 (4 VGPRs)
typedef __attribute__((ext_vector_type(4))) float    f32x4;
typedef __attribute__((ext_vector_type(4))) uint32_t u32x4;
typedef __attribute__((ext_vector_type(8))) unsigned short ushort8;

__device__ __forceinline__ unsigned short f32_to_bf16(float f) {
    uint32_t u = __float_as_uint(f);
    u = (u + 0x7FFFu + ((u >> 16) & 1u)) >> 16;   // RNE
    return (unsigned short)u;
}

// packed f32x2 -> bf16x2 (v_cvt_pk_bf16_f32 on gfx950), a in low 16 bits
__device__ __forceinline__ uint32_t pk_bf16(float a, float b) {
    union { __hip_bfloat162 h2; uint32_t u; } cv;
    cv.h2 = __float22bfloat162_rn(make_float2(a, b));
    return cv.u;
}

// ---------------- kernel 1: prep — Wopt fragment-shuffle + Wout transpose ----------------
// Wopt layout: [ksg(16)][ct(16)][lane(64)][8 bf16] — per K-step a wave's 4 B-frag
// loads are one contiguous 2KB stream. value = Wcat[col=ct*16+(lane&15)]
// [k = ksg*32+(lane>>4)*8+j], Wcat = concat(Wu,Wv) along k.
__global__ void prep(const float* __restrict__ Wu, const float* __restrict__ Wv,
                     const float* __restrict__ Wout,
                     unsigned short* __restrict__ Wopt, float* __restrict__ WoutT) {
    int bid = blockIdx.x, tid = threadIdx.x;
    if (bid < 64) {
        int idx  = bid * 256 + tid;        // 0..16383
        int lane = idx & 63;
        int ct   = (idx >> 6) & 15;
        int ksg  = idx >> 10;
        int col  = ct * 16 + (lane & 15);
        int kg   = ksg * 32 + (lane >> 4) * 8;
        ushort8 pk;
        #pragma unroll
        for (int j = 0; j < 8; j++) {
            int k = kg + j;
            float v = (k < 256) ? Wu[col * 256 + k] : Wv[col * 256 + (k - 256)];
            pk[j] = f32_to_bf16(v);
        }
        *(ushort8*)&Wopt[(size_t)idx * 8] = pk;
    } else {
        int t2 = (bid - 64) * 256 + tid;   // 0..65535
        int j = t2 & 255, k = t2 >> 8;
        WoutT[t2] = Wout[j * 256 + k];     // WoutT[k][j] = Wout[j][k]
    }
}

// ---------------- kernel 2: dual exclusive scan: item offsets + chunk work-list ----------------
__global__ void seg_offsets(const int* __restrict__ lens, int B, int* __restrict__ off,
                            int2* __restrict__ chunks, int* __restrict__ chunk_cnt) {
    __shared__ int partL[256], partC[256];
    int tid = threadIdx.x;
    bool is64 = (B >= 3) && (lens[1] == 0) && (lens[3] == 0) && (lens[5] == 0);
    int per = (B + 255) / 256;
    int base = tid * per;
    int sL = 0, sC = 0;
    for (int i = 0; i < per; i++) {
        int idx = base + i;
        if (idx < B) {
            int l = is64 ? lens[2 * idx] : lens[idx];
            sL += l;
            sC += (l + CHUNK - 1) / CHUNK;
        }
    }
    partL[tid] = sL; partC[tid] = sC;
    __syncthreads();
    for (int d = 1; d < 256; d <<= 1) {
        int vL = partL[tid], vC = partC[tid];
        int aL = (tid >= d) ? partL[tid - d] : 0;
        int aC = (tid >= d) ? partC[tid - d] : 0;
        __syncthreads();
        partL[tid] = vL + aL; partC[tid] = vC + aC;
        __syncthreads();
    }
    int runL = partL[tid] - sL;
    int runC = partC[tid] - sC;
    for (int i = 0; i < per; i++) {
        int idx = base + i;
        if (idx < B) {
            int l = is64 ? lens[2 * idx] : lens[idx];
            off[idx] = runL;
            int n = (l + CHUNK - 1) / CHUNK;
            for (int c = 0; c < n; c++)
                chunks[runC + c] = make_int2(idx, runL + c * CHUNK);
            runC += n;
            runL += l;
        }
    }
    if (tid == 255) { off[B] = partL[255]; chunk_cnt[0] = partC[255]; }
}

// ---------------- kernel 3: fused e = We . sigmoid(Wu f + bu + Wv c) ----------------
// 256 thr (4 waves). 64 rows x 256 cols, K=512 in 4 steps of KT=128.
// LDS: 64x128 bf16 XOR-swizzled in 16B groups (group' = group ^ (row&15)):
// conflict-free b128 writes AND reads with zero padding. 8 barriers total.
__global__ __launch_bounds__(256) void fused_e(
        const float* __restrict__ feats, const float* __restrict__ ctx,
        const unsigned short* __restrict__ Wopt,
        const float* __restrict__ bu, const float* __restrict__ We,
        float* __restrict__ e_out) {
    __shared__ unsigned short a_lds[64 * 128];   // 16 KB
    __shared__ float e_part[4 * 64];

    const int tid  = threadIdx.x;
    const int lane = tid & 63;
    const int w    = tid >> 6;
    const int l15  = lane & 15;
    const int q    = lane >> 4;
    const size_t m0 = (size_t)blockIdx.x * 64;
    const int r0   = tid >> 3;          // staging row 0..31 (also r0+32)
    const int c8   = tid & 7;           // 16-float chunk within 128 cols
    const int swz  = r0 & 15;

    f32x4 acc[4][4];
    #pragma unroll
    for (int i = 0; i < 4; i++)
        #pragma unroll
        for (int j = 0; j < 4; j++)
            acc[i][j] = (f32x4)(0.0f);

    f32x4 pre[8];
    {
        const float* pA = feats + (m0 + r0) * H + c8 * 16;
        const float* pB = feats + (m0 + r0 + 32) * H + c8 * 16;
        pre[0] = *(const f32x4*)pA;       pre[1] = *(const f32x4*)(pA + 4);
        pre[2] = *(const f32x4*)(pA + 8); pre[3] = *(const f32x4*)(pA + 12);
        pre[4] = *(const f32x4*)pB;       pre[5] = *(const f32x4*)(pB + 4);
        pre[6] = *(const f32x4*)(pB + 8); pre[7] = *(const f32x4*)(pB + 12);
    }

    #pragma unroll
    for (int kt = 0; kt < 4; ++kt) {
        u32x4 g0, g1, g2, g3;
        g0[0] = pk_bf16(pre[0][0], pre[0][1]); g0[1] = pk_bf16(pre[0][2], pre[0][3]);
        g0[2] = pk_bf16(pre[1][0], pre[1][1]); g0[3] = pk_bf16(pre[1][2], pre[1][3]);
        g1[0] = pk_bf16(pre[2][0], pre[2][1]); g1[1] = pk_bf16(pre[2][2], pre[2][3]);
        g1[2] = pk_bf16(pre[3][0], pre[3][1]); g1[3] = pk_bf16(pre[3][2], pre[3][3]);
        g2[0] = pk_bf16(pre[4][0], pre[4][1]); g2[1] = pk_bf16(pre[4][2], pre[4][3]);
        g2[2] = pk_bf16(pre[5][0], pre[5][1]); g2[3] = pk_bf16(pre[5][2], pre[5][3]);
        g3[0] = pk_bf16(pre[6][0], pre[6][1]); g3[1] = pk_bf16(pre[6][2], pre[6][3]);
        g3[2] = pk_bf16(pre[7][0], pre[7][1]); g3[3] = pk_bf16(pre[7][2], pre[7][3]);

        __syncthreads();                 // prior kt's fragment reads done
        *(u32x4*)&a_lds[ r0       * 128 + (((2 * c8    ) ^ swz) * 8)] = g0;
        *(u32x4*)&a_lds[ r0       * 128 + (((2 * c8 + 1) ^ swz) * 8)] = g1;
        *(u32x4*)&a_lds[(r0 + 32) * 128 + (((2 * c8    ) ^ swz) * 8)] = g2;
        *(u32x4*)&a_lds[(r0 + 32) * 128 + (((2 * c8 + 1) ^ swz) * 8)] = g3;
        __syncthreads();                 // writes visible

        if (kt < 3) {                    // prefetch next strip; overlaps MFMA below
            const float* src = (kt + 1 < 2) ? feats : ctx;
            const int kb = ((kt + 1) & 1) * 128;
            const float* pA = src + (m0 + r0) * H + kb + c8 * 16;
            const float* pB = src + (m0 + r0 + 32) * H + kb + c8 * 16;
            pre[0] = *(const f32x4*)pA;       pre[1] = *(const f32x4*)(pA + 4);
            pre[2] = *(const f32x4*)(pA + 8); pre[3] = *(const f32x4*)(pA + 12);
            pre[4] = *(const f32x4*)pB;       pre[5] = *(const f32x4*)(pB + 4);
            pre[6] = *(const f32x4*)(pB + 8); pre[7] = *(const f32x4*)(pB + 12);
        }

        #pragma unroll
        for (int ks = 0; ks < 4; ++ks) {
            const int ksg = kt * 4 + ks;
            frag8 afr[4], bfr[4];
            #pragma unroll
            for (int ci = 0; ci < 4; ++ci)
                bfr[ci] = *(const frag8*)&Wopt[(((size_t)ksg * 16 + w * 4 + ci) * 64 + lane) * 8];
            #pragma unroll
            for (int rt = 0; rt < 4; ++rt)
                afr[rt] = *(const frag8*)&a_lds[(rt * 16 + l15) * 128 + (((ks * 4 + q) ^ l15) * 8)];
            #pragma unroll
            for (int rt = 0; rt < 4; ++rt)
                #pragma unroll
                for (int ci = 0; ci < 4; ++ci)
                    acc[rt][ci] = __builtin_amdgcn_mfma_f32_16x16x32_bf16(
                        afr[rt], bfr[ci], acc[rt][ci], 0, 0, 0);
        }
    }

    // epilogue: e_row = sum_col We[col] * sigmoid(h + bu[col])
    float buv[4], wev[4];
    #pragma unroll
    for (int ci = 0; ci < 4; ++ci) {
        int col = w * 64 + ci * 16 + l15;
        buv[ci] = bu[col];
        wev[ci] = We[col];
    }
    #pragma unroll
    for (int rt = 0; rt < 4; ++rt) {
        #pragma unroll
        for (int r = 0; r < 4; ++r) {
            float s = 0.0f;
            #pragma unroll
            for (int ci = 0; ci < 4; ++ci) {
                float h = acc[rt][ci][r] + buv[ci];
                s += wev[ci] * __builtin_amdgcn_rcpf(1.0f + __expf(-h));
            }
            s += __shfl_xor(s, 1, 64);
            s += __shfl_xor(s, 2, 64);
            s += __shfl_xor(s, 4, 64);
            s += __shfl_xor(s, 8, 64);
            if (l15 == 0) e_part[w * 64 + rt * 16 + q * 4 + r] = s;
        }
    }
    __syncthreads();
    if (tid < 64)
        e_out[m0 + tid] = e_part[tid] + e_part[64 + tid] + e_part[128 + tid] + e_part[192 + tid];
}

// ---------------- kernel 4: per-segment softmax stats; alpha written IN PLACE over e ----------------
__global__ __launch_bounds__(256) void seg_stats(
        float* __restrict__ e, const int* __restrict__ off, int B) {
    int seg = blockIdx.x * 4 + (threadIdx.x >> 6);
    int lane = threadIdx.x & 63;
    if (seg >= B) return;
    int start = off[seg];
    int len = off[seg + 1] - start;
    float m = -3.0e38f;
    for (int i = lane; i < len; i += 64) m = fmaxf(m, e[start + i]);
    #pragma unroll
    for (int o = 32; o > 0; o >>= 1) m = fmaxf(m, __shfl_xor(m, o, 64));
    float s = 0.0f;
    for (int i = lane; i < len; i += 64) s += __expf(e[start + i] - m);
    #pragma unroll
    for (int o = 32; o > 0; o >>= 1) s += __shfl_xor(s, o, 64);
    float inv = (s > 0.0f) ? 1.0f / s : 0.0f;
    for (int i = lane; i < len; i += 64) e[start + i] = __expf(e[start + i] - m) * inv;
}

// ---------------- kernel 5: chunked weighted pooling (alpha-stream, dual chains) ----------------
__global__ __launch_bounds__(256) void pool_chunks(
        const float* __restrict__ alpha, const float* __restrict__ feats,
        const int* __restrict__ off, const int2* __restrict__ chunks,
        const int* __restrict__ chunk_cnt, float* __restrict__ rst) {
    __shared__ float redf[4 * 256];
    int idx = blockIdx.x;
    if (idx >= chunk_cnt[0]) return;
    int2 en = chunks[idx];
    int seg = en.x, cstart = en.y;
    int sstart = off[seg], send = off[seg + 1];
    int clen = send - cstart;
    if (clen > CHUNK) clen = CHUNK;
    int tid = threadIdx.x, lane = tid & 63, g = tid >> 6;

    const f32x4* F = (const f32x4*)feats + (size_t)cstart * 64 + lane;
    const float* A = alpha + cstart;
    f32x4 acc0 = (f32x4)(0.0f), acc1 = (f32x4)(0.0f);
    int i = g;
    for (; i + 4 < clen; i += 8) {
        acc0 += A[i]     * F[(size_t)i * 64];
        acc1 += A[i + 4] * F[(size_t)(i + 4) * 64];
    }
    if (i < clen) acc0 += A[i] * F[(size_t)i * 64];
    acc0 += acc1;
    *(f32x4*)&redf[g * 256 + lane * 4] = acc0;
    __syncthreads();
    float v = redf[tid] + redf[256 + tid] + redf[512 + tid] + redf[768 + tid];
    if (send - sstart > CHUNK) atomicAdd(&rst[(size_t)seg * H + tid], v);
    else rst[(size_t)seg * H + tid] = v;
}

// ---------------- kernel 6: out = rst @ Wout.T (via WoutT) ----------------
#define RB 8
__global__ __launch_bounds__(256) void out_gemm(
        const float* __restrict__ rst, const float* __restrict__ WoutT,
        float* __restrict__ out) {
    __shared__ float r[RB * 256];
    const int tid = threadIdx.x;
    const size_t b0 = (size_t)blockIdx.x * RB;
    for (int i = tid; i < RB * 256; i += 256) r[i] = rst[b0 * 256 + i];
    __syncthreads();
    float acc[RB];
    #pragma unroll
    for (int j = 0; j < RB; j++) acc[j] = 0.0f;
    for (int k = 0; k < 256; k += 4) {
        f32x4 rw[RB];
        #pragma unroll
        for (int j = 0; j < RB; j++) rw[j] = *(const f32x4*)&r[j * 256 + k];
        #pragma unroll
        for (int kk = 0; kk < 4; kk++) {
            float wv = WoutT[(size_t)(k + kk) * 256 + tid];
            #pragma unroll
            for (int j = 0; j < RB; j++) acc[j] += rw[j][kk] * wv;
        }
    }
    #pragma unroll
    for (int j = 0; j < RB; j++) out[(b0 + j) * 256 + tid] = acc[j];
}

// ---------------- launch ----------------
extern "C" void kernel_launch(void* const* d_in, const int* in_sizes, int n_in,
                              void* d_out, int out_size, void* d_ws, size_t ws_size,
                              hipStream_t stream) {
    const float* feats = (const float*)d_in[0];
    const float* ctx   = (const float*)d_in[1];
    const int*   lens  = (const int*)d_in[2];
    const float* Wu    = (const float*)d_in[3];
    const float* bu    = (const float*)d_in[4];
    const float* Wv    = (const float*)d_in[5];
    const float* We    = (const float*)d_in[6];
    const float* Wout  = (const float*)d_in[7];
    float* out = (float*)d_out;

    const int N = in_sizes[0] / H;    // 204800
    const int B = in_sizes[2];        // 4096
    const int maxChunks = B + (N + CHUNK - 1) / CHUNK;

    char* w = (char*)d_ws;
    auto carve = [&](size_t bytes) {
        char* p = w;
        w += (bytes + 255) & ~(size_t)255;
        return p;
    };
    int*            off    = (int*)           carve((size_t)(B + 1) * sizeof(int));
    float*          e      = (float*)         carve((size_t)N * sizeof(float));
    float*          rst    = (float*)         carve((size_t)B * H * sizeof(float));
    unsigned short* Wopt   = (unsigned short*)carve((size_t)16 * 16 * 64 * 8 * sizeof(unsigned short));
    float*          WoutT  = (float*)         carve((size_t)H * H * sizeof(float));
    int2*           chunks = (int2*)          carve((size_t)maxChunks * sizeof(int2));
    int*            ccnt   = (int*)           carve(sizeof(int));

    hipMemsetAsync(rst, 0, (size_t)B * H * sizeof(float), stream);  // for atomic combine

    prep        <<<320,         256, 0, stream>>>(Wu, Wv, Wout, Wopt, WoutT);
    seg_offsets <<<1,           256, 0, stream>>>(lens, B, off, chunks, ccnt);
    fused_e     <<<N / 64,      256, 0, stream>>>(feats, ctx, Wopt, bu, We, e);
    seg_stats   <<<(B + 3) / 4, 256, 0, stream>>>(e, off, B);
    pool_chunks <<<maxChunks,   256, 0, stream>>>(e, feats, off, chunks, ccnt, rst);
    out_gemm    <<<B / RB,      256, 0, stream>>>(rst, WoutT, out);
}